// Round 3
// baseline (1044.209 us; speedup 1.0000x reference)
//
#include <hip/hip_runtime.h>
#include <cstdint>
#include <cstddef>

typedef unsigned long long u64;
typedef unsigned int u32;
typedef __attribute__((ext_vector_type(8))) short short8;
typedef __attribute__((ext_vector_type(4))) float f32x4;

#define NBOX 100800
#define CAND_CAP 4096

// ---------------- workspace layout (bytes) ----------------
#define OFF_WTH0 ((size_t)0)          // 1024*9*1024*2
#define OFF_WTH1 ((size_t)18874368)
#define OFF_WTH2 ((size_t)23592960)
#define OFF_WTL0 ((size_t)24772608)
#define OFF_WTL1 ((size_t)43646976)
#define OFF_WTL2 ((size_t)48365568)
#define OFF_Y0   ((size_t)49545216)   // 1024*1600*4
#define OFF_Y1   ((size_t)56098816)   // 512*6400*4
#define OFF_Y2   ((size_t)69206016)   // 256*25600*4
#define OFF_KEYS ((size_t)95420416)   // 100800*8
#define OFF_HIST ((size_t)96226816)   // 65536*4
#define OFF_META ((size_t)96488960)   // 64
#define OFF_CAND ((size_t)96489024)   // 4096*8
#define OFF_SEL  ((size_t)96521792)   // 1024
// transposed bf16 inputs (optional, if ws_size permits)
#define OFF_XTH0 ((size_t)96522816)   // 1600*1024*2  = 3276800
#define OFF_XTH1 ((size_t)99799616)   // 6400*512*2   = 6553600
#define OFF_XTH2 ((size_t)106353216)  // 25600*256*2  = 13107200
#define OFF_XTL0 ((size_t)119460416)
#define OFF_XTL1 ((size_t)122737216)
#define OFF_XTL2 ((size_t)129290816)
#define NEED_FULL ((size_t)142398016)

// ---------------- bf16 helpers (RNE, finite inputs) ----------------
__device__ __forceinline__ short f2bf(float f) {
    u32 u = __float_as_uint(f);
    u = (u + 0x7fffu + ((u >> 16) & 1u)) >> 16;
    return (short)u;
}
__device__ __forceinline__ float bf2f(short h) {
    return __uint_as_float(((u32)(unsigned short)h) << 16);
}

// ---------------- weight prep: (co,ci,3,3) f32 -> [co][tap][ci] bf16 hi/lo ----
__global__ __launch_bounds__(256) void prep_w_kernel(
    const float* __restrict__ w, short* __restrict__ wh, short* __restrict__ wl, int C)
{
    __shared__ float ws_[2304];
    int chunks = C >> 8;
    int co = blockIdx.x / chunks;
    int ci0 = (blockIdx.x % chunks) << 8;
    size_t base = ((size_t)co * C + ci0) * 9;
    for (int idx = threadIdx.x; idx < 2304; idx += 256) ws_[idx] = w[base + idx];
    __syncthreads();
    for (int idx = threadIdx.x; idx < 2304; idx += 256) {
        int tap = idx >> 8, ci = idx & 255;
        float v = ws_[ci * 9 + tap];
        short h = f2bf(v);
        short l = f2bf(v - bf2f(h));
        size_t o = ((size_t)co * 9 + tap) * C + ci0 + ci;
        wh[o] = h; wl[o] = l;
    }
}

// ---------------- input prep: [C][HW] f32 -> [pix][C] bf16 hi/lo (transpose) --
struct PrepX { const float* x; short* xh; short* xl; int C, HW, bbase, ptiles; };

__global__ __launch_bounds__(256) void prep_x_kernel(PrepX p0, PrepX p1, PrepX p2)
{
    PrepX p = (blockIdx.x >= (u32)p2.bbase) ? p2 :
              (blockIdx.x >= (u32)p1.bbase) ? p1 : p0;
    int local = blockIdx.x - p.bbase;
    int pt = local % p.ptiles, ct = local / p.ptiles;
    __shared__ short th[32][34];
    __shared__ short tl[32][34];
    for (int idx = threadIdx.x; idx < 1024; idx += 256) {
        int ci = idx >> 5, px = idx & 31;
        float v = p.x[(size_t)(ct * 32 + ci) * p.HW + pt * 32 + px];
        short h = f2bf(v);
        th[ci][px] = h;
        tl[ci][px] = f2bf(v - bf2f(h));
    }
    __syncthreads();
    for (int idx = threadIdx.x; idx < 1024; idx += 256) {
        int px = idx >> 5, ci = idx & 31;
        size_t o = (size_t)(pt * 32 + px) * p.C + ct * 32 + ci;
        p.xh[o] = th[ci][px];
        p.xl[o] = tl[ci][px];
    }
}

// ---------------- fused 3-head 3x3 conv, bf16 MFMA hi/lo 3-pass --------------
// 256 thr = 4 waves; tile 128 couts x 128 pixels (8 rows x 16 cols); Z=1.
struct ConvHead {
    const float* x; const short* xh; const short* xl;
    const short* wh; const short* wl; const float* bias; float* y;
    int C, H, W, sx, nsp, c32shift, kiters, bbase;
};

__global__ __launch_bounds__(256) void conv3x3_mfma(
    ConvHead h0, ConvHead h1, ConvHead h2, int use_xt)
{
    ConvHead h = (blockIdx.x >= (u32)h2.bbase) ? h2 :
                 (blockIdx.x >= (u32)h1.bbase) ? h1 : h0;
    const int local = blockIdx.x - h.bbase;
    const int my = local / h.nsp, sp = local - my * h.nsp;
    const int py0 = (sp / h.sx) * 8, px0 = (sp - (sp / h.sx) * h.sx) * 16;
    const int co0 = my * 128;
    const int C = h.C, H = h.H, W = h.W, HW = H * W;
    const int c32mask = (C >> 5) - 1, c32shift = h.c32shift;

    const int tid = threadIdx.x;
    const int lane = tid & 63;
    const int wave = tid >> 6;
    const int quad = lane >> 4;
    const int l15 = lane & 15;
    const int wm = wave >> 1, wn = wave & 1;

    __shared__ short As_hi[128 * 40];
    __shared__ short As_lo[128 * 40];
    __shared__ short Bs_hi[128 * 40];
    __shared__ short Bs_lo[128 * 40];

    f32x4 acc[4][4];
    #pragma unroll
    for (int i = 0; i < 4; i++)
        #pragma unroll
        for (int j = 0; j < 4; j++) acc[i][j] = (f32x4){0.f, 0.f, 0.f, 0.f};

    const int bn = tid & 127;
    const int bk2 = tid >> 7;
    const int bly = bn >> 4, blx = bn & 15;

    for (int kk = 0; kk < h.kiters; ++kk) {
        const int tap = kk >> c32shift;
        const int ci0 = (kk & c32mask) << 5;
        const int t3 = tap / 3;
        const int dy = t3 - 1, dx = tap - t3 * 3 - 1;
        const int spy = py0 + bly + dy, spx = px0 + blx + dx;
        const bool inb = (spy >= 0) && (spy < H) && (spx >= 0) && (spx < W);

        __syncthreads();
        // ---- stage A (weights) ----
        #pragma unroll
        for (int i = 0; i < 2; i++) {
            int slot = i * 256 + tid;
            int m = slot >> 2, ch = slot & 3;
            size_t go = ((size_t)(co0 + m) * 9 + tap) * C + ci0 + ch * 8;
            *(short8*)&As_hi[m * 40 + ch * 8] = *(const short8*)(h.wh + go);
            *(short8*)&As_lo[m * 40 + ch * 8] = *(const short8*)(h.wl + go);
        }
        // ---- stage B (shifted input) ----
        {
            short8 bh0 = {0,0,0,0,0,0,0,0}, bh1 = {0,0,0,0,0,0,0,0};
            short8 bl0 = {0,0,0,0,0,0,0,0}, bl1 = {0,0,0,0,0,0,0,0};
            if (inb) {
                if (use_xt) {
                    size_t ro = (size_t)(spy * W + spx) * C + ci0 + bk2 * 16;
                    const short* ph = h.xh + ro;
                    const short* pl = h.xl + ro;
                    bh0 = *(const short8*)ph; bh1 = *(const short8*)(ph + 8);
                    bl0 = *(const short8*)pl; bl1 = *(const short8*)(pl + 8);
                } else {
                    const float* xp = h.x + (size_t)(ci0 + bk2 * 16) * HW + spy * W + spx;
                    #pragma unroll
                    for (int k = 0; k < 8; k++) {
                        float v = xp[(size_t)k * HW];
                        short hh = f2bf(v); bh0[k] = hh; bl0[k] = f2bf(v - bf2f(hh));
                    }
                    #pragma unroll
                    for (int k = 0; k < 8; k++) {
                        float v = xp[(size_t)(k + 8) * HW];
                        short hh = f2bf(v); bh1[k] = hh; bl1[k] = f2bf(v - bf2f(hh));
                    }
                }
            }
            int bo = bn * 40 + bk2 * 16;
            *(short8*)&Bs_hi[bo]     = bh0;
            *(short8*)&Bs_hi[bo + 8] = bh1;
            *(short8*)&Bs_lo[bo]     = bl0;
            *(short8*)&Bs_lo[bo + 8] = bl1;
        }
        __syncthreads();
        // ---- fragments + MFMA ----
        short8 ah[4], al[4], bh[4], bl[4];
        #pragma unroll
        for (int mt = 0; mt < 4; mt++) {
            int ro = (wm * 64 + mt * 16 + l15) * 40 + quad * 8;
            ah[mt] = *(const short8*)&As_hi[ro];
            al[mt] = *(const short8*)&As_lo[ro];
        }
        #pragma unroll
        for (int nt = 0; nt < 4; nt++) {
            int ro = (wn * 64 + nt * 16 + l15) * 40 + quad * 8;
            bh[nt] = *(const short8*)&Bs_hi[ro];
            bl[nt] = *(const short8*)&Bs_lo[ro];
        }
        #pragma unroll
        for (int mt = 0; mt < 4; mt++)
            #pragma unroll
            for (int nt = 0; nt < 4; nt++) {
                acc[mt][nt] = __builtin_amdgcn_mfma_f32_16x16x32_bf16(ah[mt], bh[nt], acc[mt][nt], 0, 0, 0);
                acc[mt][nt] = __builtin_amdgcn_mfma_f32_16x16x32_bf16(ah[mt], bl[nt], acc[mt][nt], 0, 0, 0);
                acc[mt][nt] = __builtin_amdgcn_mfma_f32_16x16x32_bf16(al[mt], bh[nt], acc[mt][nt], 0, 0, 0);
            }
    }

    // ---- epilogue: D[row=quad*4+r][col=l15], store acc + bias ----
    #pragma unroll
    for (int nt = 0; nt < 4; nt++) {
        int n = wn * 64 + nt * 16 + l15;
        int py = py0 + (n >> 4), px = px0 + (n & 15);
        if (px < W) {
            #pragma unroll
            for (int mt = 0; mt < 4; mt++) {
                #pragma unroll
                for (int r = 0; r < 4; r++) {
                    int co = co0 + wm * 64 + mt * 16 + quad * 4 + r;
                    h.y[(size_t)co * HW + (size_t)py * W + px] = acc[mt][nt][r] + h.bias[co];
                }
            }
        }
    }
}

// ------- objectness-only 1x1 conv + key write + histogram (fused heads) ------
__global__ __launch_bounds__(256) void obj_kernel(
    const float* __restrict__ y0, const float* __restrict__ y1, const float* __restrict__ y2,
    const float* __restrict__ w10, const float* __restrict__ w11, const float* __restrict__ w12,
    const float* __restrict__ b10, const float* __restrict__ b11, const float* __restrict__ b12,
    u64* __restrict__ keys, u32* __restrict__ hist)
{
    int b = blockIdx.x;
    const float *y, *w1, *b1; int C, HW, base, b0;
    if (b < 7)       { y = y0; w1 = w10; b1 = b10; C = 1024; HW = 1600;  base = 0;     b0 = 0;  }
    else if (b < 32) { y = y1; w1 = w11; b1 = b11; C = 512;  HW = 6400;  base = 4800;  b0 = 7;  }
    else             { y = y2; w1 = w12; b1 = b12; C = 256;  HW = 25600; base = 24000; b0 = 32; }

    __shared__ float wv[3 * 1024];
    for (int idx = threadIdx.x; idx < 3 * C; idx += 256)
        wv[idx] = w1[((size_t)(idx / C) * 85 + 4) * C + (idx % C)];
    __syncthreads();
    int p = (b - b0) * 256 + threadIdx.x;
    if (p >= HW) return;
    float a0 = b1[4], a1 = b1[89], a2 = b1[174];
    const float* yp = y + p;
    for (int ci = 0; ci < C; ci++) {
        float v = yp[(size_t)ci * HW];
        a0 = fmaf(v, wv[ci], a0);
        a1 = fmaf(v, wv[C + ci], a1);
        a2 = fmaf(v, wv[2 * C + ci], a2);
    }
    float sc[3] = {a0, a1, a2};
    #pragma unroll
    for (int a = 0; a < 3; a++) {
        float s = 1.0f / (1.0f + expf(-sc[a]));
        u32 bi = (u32)(base + a * HW + p);
        u64 k = ((u64)__float_as_uint(s) << 32) | (u64)(0xFFFFFFFFu - bi);
        keys[bi] = k;
        atomicAdd(&hist[(u32)(k >> 48)], 1u);
    }
}

// ---------------- top-256 selection ----------------
__global__ __launch_bounds__(256) void select_kernel(const u32* __restrict__ hist,
                                                     u32* __restrict__ meta)
{
    __shared__ u32 csum[256];
    int t = threadIdx.x;
    u32 s = 0;
    for (int i = 0; i < 256; i++) s += hist[t * 256 + i];
    csum[t] = s;
    __syncthreads();
    if (t == 0) {
        u32 cum = 0; int chunk = 255;
        for (; chunk > 0; chunk--) {
            if (cum + csum[chunk] >= 256u) break;
            cum += csum[chunk];
        }
        int B = chunk * 256;
        u32 cumAbove = cum;
        for (int bb = chunk * 256 + 255; bb >= chunk * 256; bb--) {
            u32 h = hist[bb];
            if (cumAbove + h >= 256u) { B = bb; break; }
            cumAbove += h;
        }
        meta[0] = (u32)B;
        meta[1] = cumAbove;
    }
}

__global__ __launch_bounds__(256) void compact_kernel(
    const u64* __restrict__ keys, int n, const u32* __restrict__ meta,
    u64* __restrict__ cand, u32* __restrict__ count)
{
    int i = blockIdx.x * blockDim.x + threadIdx.x;
    if (i < n) {
        u64 k = keys[i];
        if ((u32)(k >> 48) >= meta[0]) {
            u32 pos = atomicAdd(count, 1u);
            if (pos < CAND_CAP) cand[pos] = k;
        }
    }
}

__global__ __launch_bounds__(1024) void sort_select_kernel(
    const u64* __restrict__ cand, const u32* __restrict__ meta,
    u32* __restrict__ sel)
{
    __shared__ u64 sk[CAND_CAP];
    int n = (int)meta[2];
    if (n > CAND_CAP) n = CAND_CAP;
    for (int i = threadIdx.x; i < CAND_CAP; i += 1024)
        sk[i] = (i < n) ? cand[i] : 0ull;
    __syncthreads();
    for (int k = 2; k <= CAND_CAP; k <<= 1) {
        for (int j = k >> 1; j > 0; j >>= 1) {
            for (int i = threadIdx.x; i < CAND_CAP; i += 1024) {
                int ixj = i ^ j;
                if (ixj > i) {
                    u64 a = sk[i], c = sk[ixj];
                    bool sw = ((i & k) == 0) ? (a > c) : (a < c);
                    if (sw) { sk[i] = c; sk[ixj] = a; }
                }
            }
            __syncthreads();
        }
    }
    if (threadIdx.x < 256) {
        u64 k = sk[CAND_CAP - 1 - threadIdx.x];
        sel[threadIdx.x] = 0xFFFFFFFFu - (u32)(k & 0xFFFFFFFFull);
    }
}

// ---------------- final: full 85-ch 1x1 conv + decode for the 256 winners ---
__global__ __launch_bounds__(256) void final_kernel(
    const float* __restrict__ y0, const float* __restrict__ y1, const float* __restrict__ y2,
    const float* __restrict__ w10, const float* __restrict__ w11, const float* __restrict__ w12,
    const float* __restrict__ b10, const float* __restrict__ b11, const float* __restrict__ b12,
    const u32* __restrict__ sel, float* __restrict__ out)
{
    int b = blockIdx.x;
    u32 bi = sel[b];
    const float *y, *w1, *b1;
    int C, H, W, base; float ratio;
    float anchs[6];
    if (bi < 4800u) {
        y = y0; w1 = w10; b1 = b10; C = 1024; H = 40; W = 40; base = 0; ratio = 32.f;
        anchs[0]=116.f; anchs[1]=90.f; anchs[2]=156.f; anchs[3]=198.f; anchs[4]=373.f; anchs[5]=326.f;
    } else if (bi < 24000u) {
        y = y1; w1 = w11; b1 = b11; C = 512; H = 80; W = 80; base = 4800; ratio = 16.f;
        anchs[0]=30.f; anchs[1]=61.f; anchs[2]=62.f; anchs[3]=45.f; anchs[4]=59.f; anchs[5]=119.f;
    } else {
        y = y2; w1 = w12; b1 = b12; C = 256; H = 160; W = 160; base = 24000; ratio = 8.f;
        anchs[0]=10.f; anchs[1]=13.f; anchs[2]=16.f; anchs[3]=30.f; anchs[4]=33.f; anchs[5]=23.f;
    }
    int HW = H * W;
    int r = (int)bi - base;
    int a = r / HW, p = r % HW;
    __shared__ float ys[256];
    int c = threadIdx.x;
    float acc = 0.f;
    const float* wrow = w1 + (size_t)(a * 85 + (c < 85 ? c : 0)) * C;
    for (int ci0 = 0; ci0 < C; ci0 += 256) {
        __syncthreads();
        ys[c] = y[(size_t)(ci0 + c) * HW + p];
        __syncthreads();
        if (c < 85)
            for (int ci = 0; ci < 256; ci++) acc = fmaf(ys[ci], wrow[ci0 + ci], acc);
    }
    if (c < 85) {
        float v = acc + b1[a * 85 + c];
        float s = 1.0f / (1.0f + expf(-v));
        int py = p / W, px = p - (p / W) * W;
        float o;
        if (c == 0)      o = (s * 2.0f - 0.5f + (float)px) * ratio;
        else if (c == 1) o = (s * 2.0f - 0.5f + (float)py) * ratio;
        else if (c == 2) { float t = s * 2.0f; o = t * t * anchs[a * 2]; }
        else if (c == 3) { float t = s * 2.0f; o = t * t * anchs[a * 2 + 1]; }
        else             o = s;
        out[(size_t)b * 85 + c] = o;
    }
}

// ---------------- launch ----------------
extern "C" void kernel_launch(void* const* d_in, const int* in_sizes, int n_in,
                              void* d_out, int out_size, void* d_ws, size_t ws_size,
                              hipStream_t stream)
{
    const float* feat0 = (const float*)d_in[0];   // (256,160,160)
    const float* feat1 = (const float*)d_in[1];   // (512,80,80)
    const float* feat2 = (const float*)d_in[2];   // (1024,40,40)
    const float* w3_0 = (const float*)d_in[3];  const float* b3_0 = (const float*)d_in[4];
    const float* w1_0 = (const float*)d_in[5];  const float* b1_0 = (const float*)d_in[6];
    const float* w3_1 = (const float*)d_in[7];  const float* b3_1 = (const float*)d_in[8];
    const float* w1_1 = (const float*)d_in[9];  const float* b1_1 = (const float*)d_in[10];
    const float* w3_2 = (const float*)d_in[11]; const float* b3_2 = (const float*)d_in[12];
    const float* w1_2 = (const float*)d_in[13]; const float* b1_2 = (const float*)d_in[14];

    char* ws = (char*)d_ws;
    short* wth0 = (short*)(ws + OFF_WTH0);
    short* wth1 = (short*)(ws + OFF_WTH1);
    short* wth2 = (short*)(ws + OFF_WTH2);
    short* wtl0 = (short*)(ws + OFF_WTL0);
    short* wtl1 = (short*)(ws + OFF_WTL1);
    short* wtl2 = (short*)(ws + OFF_WTL2);
    float* y0   = (float*)(ws + OFF_Y0);
    float* y1   = (float*)(ws + OFF_Y1);
    float* y2   = (float*)(ws + OFF_Y2);
    u64*   keys = (u64*)  (ws + OFF_KEYS);
    u32*   hist = (u32*)  (ws + OFF_HIST);
    u32*   meta = (u32*)  (ws + OFF_META);
    u64*   cand = (u64*)  (ws + OFF_CAND);
    u32*   sel  = (u32*)  (ws + OFF_SEL);

    const int use_xt = (ws_size >= NEED_FULL) ? 1 : 0;
    short* xth0 = (short*)(ws + OFF_XTH0);
    short* xth1 = (short*)(ws + OFF_XTH1);
    short* xth2 = (short*)(ws + OFF_XTH2);
    short* xtl0 = (short*)(ws + OFF_XTL0);
    short* xtl1 = (short*)(ws + OFF_XTL1);
    short* xtl2 = (short*)(ws + OFF_XTL2);

    hipMemsetAsync(ws + OFF_HIST, 0, 262144 + 64, stream);

    // weight transforms
    prep_w_kernel<<<4096, 256, 0, stream>>>(w3_0, wth0, wtl0, 1024);
    prep_w_kernel<<<1024, 256, 0, stream>>>(w3_1, wth1, wtl1, 512);
    prep_w_kernel<<<256,  256, 0, stream>>>(w3_2, wth2, wtl2, 256);

    // input transpose + bf16 split (optional)
    if (use_xt) {
        PrepX p0 = {feat2, xth0, xtl0, 1024, 1600,  0,    50};
        PrepX p1 = {feat1, xth1, xtl1, 512,  6400,  1600, 200};
        PrepX p2 = {feat0, xth2, xtl2, 256,  25600, 4800, 800};
        prep_x_kernel<<<11200, 256, 0, stream>>>(p0, p1, p2);
    }

    // fused 3-head 3x3 conv
    // head0: C=1024 40x40  sx=3 sy=5  nsp=15  gy=8 -> 120 blocks, 288 k-iters
    // head1: C=512  80x80  sx=5 sy=10 nsp=50  gy=4 -> 200 blocks, 144 k-iters
    // head2: C=256 160x160 sx=10 sy=20 nsp=200 gy=2 -> 400 blocks, 72 k-iters
    ConvHead h0 = {feat2, xth0, xtl0, wth0, wtl0, b3_0, y0, 1024, 40,  40,  3,  15,  5, 288, 0};
    ConvHead h1 = {feat1, xth1, xtl1, wth1, wtl1, b3_1, y1, 512,  80,  80,  5,  50,  4, 144, 120};
    ConvHead h2 = {feat0, xth2, xtl2, wth2, wtl2, b3_2, y2, 256,  160, 160, 10, 200, 3, 72,  320};
    conv3x3_mfma<<<720, 256, 0, stream>>>(h0, h1, h2, use_xt);

    // objectness + keys + histogram (fused heads)
    obj_kernel<<<132, 256, 0, stream>>>(y0, y1, y2, w1_0, w1_1, w1_2,
                                        b1_0, b1_1, b1_2, keys, hist);

    // top-256
    select_kernel<<<1, 256, 0, stream>>>(hist, meta);
    compact_kernel<<<(NBOX + 255) / 256, 256, 0, stream>>>(keys, NBOX, meta, cand, meta + 2);
    sort_select_kernel<<<1, 1024, 0, stream>>>(cand, meta, sel);

    // full 85-channel compute + decode for winners only
    final_kernel<<<256, 256, 0, stream>>>(y0, y1, y2, w1_0, w1_1, w1_2,
                                          b1_0, b1_1, b1_2, sel, (float*)d_out);
}

// Round 5
// 715.718 us; speedup vs baseline: 1.4590x; 1.4590x over previous
//
#include <hip/hip_runtime.h>
#include <cstdint>
#include <cstddef>

typedef unsigned long long u64;
typedef unsigned int u32;
typedef __attribute__((ext_vector_type(8))) short short8;
typedef __attribute__((ext_vector_type(4))) float f32x4;

#define NBOX 100800
#define CAND_CAP 4096
#define APAD 36   // A row stride (shorts)
#define BPAD 36   // hood pixel stride (shorts)

// ---------------- workspace layout (bytes) ----------------
#define OFF_WTH0 ((size_t)0)
#define OFF_WTH1 ((size_t)18874368)
#define OFF_WTH2 ((size_t)23592960)
#define OFF_WTL0 ((size_t)24772608)
#define OFF_WTL1 ((size_t)43646976)
#define OFF_WTL2 ((size_t)48365568)
#define OFF_Y0   ((size_t)49545216)
#define OFF_Y1   ((size_t)56098816)
#define OFF_Y2   ((size_t)69206016)
#define OFF_KEYS ((size_t)95420416)
#define OFF_HIST ((size_t)96226816)   // 262144
#define OFF_META ((size_t)96488960)   // 64
#define OFF_LOG  ((size_t)96489024)   // 100800*4 = 403200 (zeroed with hist+meta)
#define OFF_CAND ((size_t)96892224)   // 32768
#define OFF_SEL  ((size_t)96924992)   // 1024
#define OFF_XTH0 ((size_t)96926016)
#define OFF_XTH1 ((size_t)100202816)
#define OFF_XTH2 ((size_t)106756416)
#define OFF_XTL0 ((size_t)119863616)
#define OFF_XTL1 ((size_t)123140416)
#define OFF_XTL2 ((size_t)129694016)
#define NEED_FULL ((size_t)142801216)
#define MEMSET_LEN ((size_t)(262144 + 64 + 403200))

// ---------------- bf16 helpers (RNE, finite inputs) ----------------
__device__ __forceinline__ short f2bf(float f) {
    u32 u = __float_as_uint(f);
    u = (u + 0x7fffu + ((u >> 16) & 1u)) >> 16;
    return (short)u;
}
__device__ __forceinline__ float bf2f(short h) {
    return __uint_as_float(((u32)(unsigned short)h) << 16);
}

// ---------------- weight prep: (co,ci,3,3) f32 -> [co][tap][ci] bf16 hi/lo ----
__global__ __launch_bounds__(256) void prep_w_kernel(
    const float* __restrict__ w, short* __restrict__ wh, short* __restrict__ wl, int C)
{
    __shared__ float ws_[2304];
    int chunks = C >> 8;
    int co = blockIdx.x / chunks;
    int ci0 = (blockIdx.x % chunks) << 8;
    size_t base = ((size_t)co * C + ci0) * 9;
    for (int idx = threadIdx.x; idx < 2304; idx += 256) ws_[idx] = w[base + idx];
    __syncthreads();
    for (int idx = threadIdx.x; idx < 2304; idx += 256) {
        int tap = idx >> 8, ci = idx & 255;
        float v = ws_[ci * 9 + tap];
        short h = f2bf(v);
        short l = f2bf(v - bf2f(h));
        size_t o = ((size_t)co * 9 + tap) * C + ci0 + ci;
        wh[o] = h; wl[o] = l;
    }
}

// ---------------- input prep: [C][HW] f32 -> [pix][C] bf16 hi/lo (transpose) --
struct PrepX { const float* x; short* xh; short* xl; int C, HW, bbase, ptiles; };

__global__ __launch_bounds__(256) void prep_x_kernel(PrepX p0, PrepX p1, PrepX p2)
{
    PrepX p = (blockIdx.x >= (u32)p2.bbase) ? p2 :
              (blockIdx.x >= (u32)p1.bbase) ? p1 : p0;
    int local = blockIdx.x - p.bbase;
    int pt = local % p.ptiles, ct = local / p.ptiles;
    __shared__ short th[32][34];
    __shared__ short tl[32][34];
    for (int idx = threadIdx.x; idx < 1024; idx += 256) {
        int ci = idx >> 5, px = idx & 31;
        float v = p.x[(size_t)(ct * 32 + ci) * p.HW + pt * 32 + px];
        short h = f2bf(v);
        th[ci][px] = h;
        tl[ci][px] = f2bf(v - bf2f(h));
    }
    __syncthreads();
    for (int idx = threadIdx.x; idx < 1024; idx += 256) {
        int px = idx >> 5, ci = idx & 31;
        size_t o = (size_t)(pt * 32 + px) * p.C + ct * 32 + ci;
        p.xh[o] = th[ci][px];
        p.xl[o] = tl[ci][px];
    }
}

// ------- fused 3-head 3x3 conv, bf16 MFMA hi/lo 3-pass, tap-reuse hood -------
// 256 thr = 4 waves; tile 128 couts x 128 pixels (8 rows x 16 cols).
// Swizzle: my = local & nco_mask so same-XCD blocks share the weight co-tile.
// Epilogue fuses the objectness 1x1 partial dot (atomicAdd into logits).
struct ConvHead {
    const float* x; const short* xh; const short* xl;
    const short* wh; const short* wl; const float* bias;
    const float* w1; float* y;
    int C, H, W, sx, nco_mask, nco_shift, chunks, bbase, lbase;
};

__global__ __launch_bounds__(256, 3) void conv3x3_mfma(
    ConvHead h0, ConvHead h1, ConvHead h2, float* __restrict__ logits, int use_xt)
{
    ConvHead h = (blockIdx.x >= (u32)h2.bbase) ? h2 :
                 (blockIdx.x >= (u32)h1.bbase) ? h1 : h0;
    const int local = blockIdx.x - h.bbase;
    const int my = local & h.nco_mask;
    const int sp = local >> h.nco_shift;
    const int ty = sp / h.sx;
    const int tx = sp - ty * h.sx;
    const int py0 = ty * 8, px0 = tx * 16;
    const int co0 = my * 128;
    const int C = h.C, H = h.H, W = h.W, HW = H * W;

    const int tid = threadIdx.x;
    const int lane = tid & 63;
    const int wave = tid >> 6;
    const int quad = lane >> 4;
    const int l15 = lane & 15;
    const int wm = wave >> 1, wn = wave & 1;

    __shared__ short As_hi[128 * APAD];
    __shared__ short As_lo[128 * APAD];
    __shared__ short Bh_hi[180 * BPAD];   // 10 x 18 pixel hood x 32 ch
    __shared__ short Bh_lo[180 * BPAD];
    __shared__ float wobj[3][128];

    f32x4 acc[4][4];
    #pragma unroll
    for (int i = 0; i < 4; i++)
        #pragma unroll
        for (int j = 0; j < 4; j++) acc[i][j] = (f32x4){0.f, 0.f, 0.f, 0.f};

    for (int ch = 0; ch < h.chunks; ++ch) {
        const int ci0 = ch << 5;
        __syncthreads();   // hood of previous chunk fully consumed
        // ---- stage hood: 180 pixels x 32 channels, hi/lo, zero-padded ----
        for (int idx = tid; idx < 360; idx += 256) {
            int hp = idx >> 1, half = idx & 1;
            int hy = hp / 18, hx = hp - hy * 18;
            int gy = py0 - 1 + hy, gx = px0 - 1 + hx;
            short8 vh0 = {0,0,0,0,0,0,0,0}, vh1 = {0,0,0,0,0,0,0,0};
            short8 vl0 = {0,0,0,0,0,0,0,0}, vl1 = {0,0,0,0,0,0,0,0};
            if (gy >= 0 && gy < H && gx >= 0 && gx < W) {
                if (use_xt) {
                    size_t ro = (size_t)(gy * W + gx) * C + ci0 + half * 16;
                    const short* ph = h.xh + ro;
                    const short* pl = h.xl + ro;
                    vh0 = *(const short8*)ph; vh1 = *(const short8*)(ph + 8);
                    vl0 = *(const short8*)pl; vl1 = *(const short8*)(pl + 8);
                } else {
                    const float* xp = h.x + (size_t)(ci0 + half * 16) * HW + gy * W + gx;
                    #pragma unroll
                    for (int k = 0; k < 8; k++) {
                        float v = xp[(size_t)k * HW];
                        short hh = f2bf(v); vh0[k] = hh; vl0[k] = f2bf(v - bf2f(hh));
                    }
                    #pragma unroll
                    for (int k = 0; k < 8; k++) {
                        float v = xp[(size_t)(k + 8) * HW];
                        short hh = f2bf(v); vh1[k] = hh; vl1[k] = f2bf(v - bf2f(hh));
                    }
                }
            }
            int bo = hp * BPAD + half * 16;
            *(short8*)&Bh_hi[bo]     = vh0;
            *(short8*)&Bh_hi[bo + 8] = vh1;
            *(short8*)&Bh_lo[bo]     = vl0;
            *(short8*)&Bh_lo[bo + 8] = vl1;
        }
        for (int tap = 0; tap < 9; ++tap) {
            __syncthreads();   // A[tap-1] frag reads done; hood visible (tap 0)
            // ---- stage A (weights for this tap) ----
            #pragma unroll
            for (int i = 0; i < 2; i++) {
                int slot = i * 256 + tid;
                int m = slot >> 2, c8 = slot & 3;
                size_t go = ((size_t)(co0 + m) * 9 + tap) * C + ci0 + c8 * 8;
                *(short8*)&As_hi[m * APAD + c8 * 8] = *(const short8*)(h.wh + go);
                *(short8*)&As_lo[m * APAD + c8 * 8] = *(const short8*)(h.wl + go);
            }
            __syncthreads();
            const int dy = tap / 3, dx = tap - dy * 3;   // 0..2
            short8 ah[4], al[4], bh[4], bl[4];
            #pragma unroll
            for (int mt = 0; mt < 4; mt++) {
                int ro = (wm * 64 + mt * 16 + l15) * APAD + quad * 8;
                ah[mt] = *(const short8*)&As_hi[ro];
                al[mt] = *(const short8*)&As_lo[ro];
            }
            #pragma unroll
            for (int nt = 0; nt < 4; nt++) {
                int n = wn * 64 + nt * 16 + l15;
                int ro = ((((n >> 4) + dy) * 18) + (n & 15) + dx) * BPAD + quad * 8;
                bh[nt] = *(const short8*)&Bh_hi[ro];
                bl[nt] = *(const short8*)&Bh_lo[ro];
            }
            #pragma unroll
            for (int mt = 0; mt < 4; mt++)
                #pragma unroll
                for (int nt = 0; nt < 4; nt++) {
                    acc[mt][nt] = __builtin_amdgcn_mfma_f32_16x16x32_bf16(ah[mt], bh[nt], acc[mt][nt], 0, 0, 0);
                    acc[mt][nt] = __builtin_amdgcn_mfma_f32_16x16x32_bf16(ah[mt], bl[nt], acc[mt][nt], 0, 0, 0);
                    acc[mt][nt] = __builtin_amdgcn_mfma_f32_16x16x32_bf16(al[mt], bh[nt], acc[mt][nt], 0, 0, 0);
                }
        }
    }

    // ---- epilogue: y = acc + bias; fused objectness partial dot ----
    // FIX(R4): strided loop — block has 256 threads, need all 384 entries.
    for (int idx = tid; idx < 384; idx += 256) {
        int a = idx >> 7, m = idx & 127;
        wobj[a][m] = h.w1[(size_t)(a * 85 + 4) * C + co0 + m];
    }
    __syncthreads();
    #pragma unroll
    for (int nt = 0; nt < 4; nt++) {
        int n = wn * 64 + nt * 16 + l15;
        int py = py0 + (n >> 4), px = px0 + (n & 15);
        if (px < W) {
            int p = py * W + px;
            float s0 = 0.f, s1 = 0.f, s2 = 0.f;
            #pragma unroll
            for (int mt = 0; mt < 4; mt++) {
                #pragma unroll
                for (int r = 0; r < 4; r++) {
                    int m = wm * 64 + mt * 16 + quad * 4 + r;
                    int co = co0 + m;
                    float yv = acc[mt][nt][r] + h.bias[co];
                    h.y[(size_t)co * HW + p] = yv;
                    s0 = fmaf(yv, wobj[0][m], s0);
                    s1 = fmaf(yv, wobj[1][m], s1);
                    s2 = fmaf(yv, wobj[2][m], s2);
                }
            }
            atomicAdd(&logits[h.lbase + p], s0);
            atomicAdd(&logits[h.lbase + HW + p], s1);
            atomicAdd(&logits[h.lbase + 2 * HW + p], s2);
        }
    }
}

// ---------------- keys: logits -> sigmoid -> sort key + histogram ------------
__global__ __launch_bounds__(256) void keys_kernel(
    const float* __restrict__ logits,
    const float* __restrict__ b10, const float* __restrict__ b11, const float* __restrict__ b12,
    u64* __restrict__ keys, u32* __restrict__ hist)
{
    int i = blockIdx.x * 256 + threadIdx.x;
    if (i >= NBOX) return;
    float bias;
    if (i < 4800)       bias = b10[(i / 1600) * 85 + 4];
    else if (i < 24000) bias = b11[((i - 4800) / 6400) * 85 + 4];
    else                bias = b12[((i - 24000) / 25600) * 85 + 4];
    float s = 1.0f / (1.0f + expf(-(logits[i] + bias)));
    u64 k = ((u64)__float_as_uint(s) << 32) | (u64)(0xFFFFFFFFu - (u32)i);
    keys[i] = k;
    atomicAdd(&hist[(u32)(k >> 48)], 1u);
}

// ---------------- top-256 selection ----------------
__global__ __launch_bounds__(256) void select_kernel(const u32* __restrict__ hist,
                                                     u32* __restrict__ meta)
{
    __shared__ u32 csum[256];
    int t = threadIdx.x;
    u32 s = 0;
    for (int i = 0; i < 256; i++) s += hist[t * 256 + i];
    csum[t] = s;
    __syncthreads();
    if (t == 0) {
        u32 cum = 0; int chunk = 255;
        for (; chunk > 0; chunk--) {
            if (cum + csum[chunk] >= 256u) break;
            cum += csum[chunk];
        }
        int B = chunk * 256;
        u32 cumAbove = cum;
        for (int bb = chunk * 256 + 255; bb >= chunk * 256; bb--) {
            u32 h = hist[bb];
            if (cumAbove + h >= 256u) { B = bb; break; }
            cumAbove += h;
        }
        meta[0] = (u32)B;
        meta[1] = cumAbove;
    }
}

__global__ __launch_bounds__(256) void compact_kernel(
    const u64* __restrict__ keys, int n, const u32* __restrict__ meta,
    u64* __restrict__ cand, u32* __restrict__ count)
{
    int i = blockIdx.x * blockDim.x + threadIdx.x;
    if (i < n) {
        u64 k = keys[i];
        if ((u32)(k >> 48) >= meta[0]) {
            u32 pos = atomicAdd(count, 1u);
            if (pos < CAND_CAP) cand[pos] = k;
        }
    }
}

__global__ __launch_bounds__(1024) void sort_select_kernel(
    const u64* __restrict__ cand, const u32* __restrict__ meta,
    u32* __restrict__ sel)
{
    __shared__ u64 sk[CAND_CAP];
    int n = (int)meta[2];
    if (n > CAND_CAP) n = CAND_CAP;
    for (int i = threadIdx.x; i < CAND_CAP; i += 1024)
        sk[i] = (i < n) ? cand[i] : 0ull;
    __syncthreads();
    for (int k = 2; k <= CAND_CAP; k <<= 1) {
        for (int j = k >> 1; j > 0; j >>= 1) {
            for (int i = threadIdx.x; i < CAND_CAP; i += 1024) {
                int ixj = i ^ j;
                if (ixj > i) {
                    u64 a = sk[i], c = sk[ixj];
                    bool sw = ((i & k) == 0) ? (a > c) : (a < c);
                    if (sw) { sk[i] = c; sk[ixj] = a; }
                }
            }
            __syncthreads();
        }
    }
    if (threadIdx.x < 256) {
        u64 k = sk[CAND_CAP - 1 - threadIdx.x];
        sel[threadIdx.x] = 0xFFFFFFFFu - (u32)(k & 0xFFFFFFFFull);
    }
}

// ---------------- final: full 85-ch 1x1 conv + decode for the 256 winners ---
__global__ __launch_bounds__(256) void final_kernel(
    const float* __restrict__ y0, const float* __restrict__ y1, const float* __restrict__ y2,
    const float* __restrict__ w10, const float* __restrict__ w11, const float* __restrict__ w12,
    const float* __restrict__ b10, const float* __restrict__ b11, const float* __restrict__ b12,
    const u32* __restrict__ sel, float* __restrict__ out)
{
    int b = blockIdx.x;
    u32 bi = sel[b];
    const float *y, *w1, *b1;
    int C, H, W, base; float ratio;
    float anchs[6];
    if (bi < 4800u) {
        y = y0; w1 = w10; b1 = b10; C = 1024; H = 40; W = 40; base = 0; ratio = 32.f;
        anchs[0]=116.f; anchs[1]=90.f; anchs[2]=156.f; anchs[3]=198.f; anchs[4]=373.f; anchs[5]=326.f;
    } else if (bi < 24000u) {
        y = y1; w1 = w11; b1 = b11; C = 512; H = 80; W = 80; base = 4800; ratio = 16.f;
        anchs[0]=30.f; anchs[1]=61.f; anchs[2]=62.f; anchs[3]=45.f; anchs[4]=59.f; anchs[5]=119.f;
    } else {
        y = y2; w1 = w12; b1 = b12; C = 256; H = 160; W = 160; base = 24000; ratio = 8.f;
        anchs[0]=10.f; anchs[1]=13.f; anchs[2]=16.f; anchs[3]=30.f; anchs[4]=33.f; anchs[5]=23.f;
    }
    int HW = H * W;
    int r = (int)bi - base;
    int a = r / HW, p = r % HW;
    __shared__ float ys[256];
    int c = threadIdx.x;
    float acc = 0.f;
    const float* wrow = w1 + (size_t)(a * 85 + (c < 85 ? c : 0)) * C;
    for (int ci0 = 0; ci0 < C; ci0 += 256) {
        __syncthreads();
        ys[c] = y[(size_t)(ci0 + c) * HW + p];
        __syncthreads();
        if (c < 85)
            for (int ci = 0; ci < 256; ci++) acc = fmaf(ys[ci], wrow[ci0 + ci], acc);
    }
    if (c < 85) {
        float v = acc + b1[a * 85 + c];
        float s = 1.0f / (1.0f + expf(-v));
        int py = p / W, px = p - (p / W) * W;
        float o;
        if (c == 0)      o = (s * 2.0f - 0.5f + (float)px) * ratio;
        else if (c == 1) o = (s * 2.0f - 0.5f + (float)py) * ratio;
        else if (c == 2) { float t = s * 2.0f; o = t * t * anchs[a * 2]; }
        else if (c == 3) { float t = s * 2.0f; o = t * t * anchs[a * 2 + 1]; }
        else             o = s;
        out[(size_t)b * 85 + c] = o;
    }
}

// ---------------- launch ----------------
extern "C" void kernel_launch(void* const* d_in, const int* in_sizes, int n_in,
                              void* d_out, int out_size, void* d_ws, size_t ws_size,
                              hipStream_t stream)
{
    const float* feat0 = (const float*)d_in[0];   // (256,160,160)
    const float* feat1 = (const float*)d_in[1];   // (512,80,80)
    const float* feat2 = (const float*)d_in[2];   // (1024,40,40)
    const float* w3_0 = (const float*)d_in[3];  const float* b3_0 = (const float*)d_in[4];
    const float* w1_0 = (const float*)d_in[5];  const float* b1_0 = (const float*)d_in[6];
    const float* w3_1 = (const float*)d_in[7];  const float* b3_1 = (const float*)d_in[8];
    const float* w1_1 = (const float*)d_in[9];  const float* b1_1 = (const float*)d_in[10];
    const float* w3_2 = (const float*)d_in[11]; const float* b3_2 = (const float*)d_in[12];
    const float* w1_2 = (const float*)d_in[13]; const float* b1_2 = (const float*)d_in[14];

    char* ws = (char*)d_ws;
    short* wth0 = (short*)(ws + OFF_WTH0);
    short* wth1 = (short*)(ws + OFF_WTH1);
    short* wth2 = (short*)(ws + OFF_WTH2);
    short* wtl0 = (short*)(ws + OFF_WTL0);
    short* wtl1 = (short*)(ws + OFF_WTL1);
    short* wtl2 = (short*)(ws + OFF_WTL2);
    float* y0   = (float*)(ws + OFF_Y0);
    float* y1   = (float*)(ws + OFF_Y1);
    float* y2   = (float*)(ws + OFF_Y2);
    u64*   keys = (u64*)  (ws + OFF_KEYS);
    u32*   hist = (u32*)  (ws + OFF_HIST);
    u32*   meta = (u32*)  (ws + OFF_META);
    float* logits = (float*)(ws + OFF_LOG);
    u64*   cand = (u64*)  (ws + OFF_CAND);
    u32*   sel  = (u32*)  (ws + OFF_SEL);

    const int use_xt = (ws_size >= NEED_FULL) ? 1 : 0;
    short* xth0 = (short*)(ws + OFF_XTH0);
    short* xth1 = (short*)(ws + OFF_XTH1);
    short* xth2 = (short*)(ws + OFF_XTH2);
    short* xtl0 = (short*)(ws + OFF_XTL0);
    short* xtl1 = (short*)(ws + OFF_XTL1);
    short* xtl2 = (short*)(ws + OFF_XTL2);

    hipMemsetAsync(ws + OFF_HIST, 0, MEMSET_LEN, stream);

    // weight transforms
    prep_w_kernel<<<4096, 256, 0, stream>>>(w3_0, wth0, wtl0, 1024);
    prep_w_kernel<<<1024, 256, 0, stream>>>(w3_1, wth1, wtl1, 512);
    prep_w_kernel<<<256,  256, 0, stream>>>(w3_2, wth2, wtl2, 256);

    // input transpose + bf16 split
    if (use_xt) {
        PrepX p0 = {feat2, xth0, xtl0, 1024, 1600,  0,    50};
        PrepX p1 = {feat1, xth1, xtl1, 512,  6400,  1600, 200};
        PrepX p2 = {feat0, xth2, xtl2, 256,  25600, 4800, 800};
        prep_x_kernel<<<11200, 256, 0, stream>>>(p0, p1, p2);
    }

    // fused 3-head 3x3 conv (+ objectness partials)
    // head0: 8 co-tiles x 15 sp = 120 blocks; head1: 4 x 50 = 200; head2: 2 x 200 = 400
    ConvHead h0 = {feat2, xth0, xtl0, wth0, wtl0, b3_0, w1_0, y0, 1024, 40,  40,  3,  7, 3, 32, 0,   0};
    ConvHead h1 = {feat1, xth1, xtl1, wth1, wtl1, b3_1, w1_1, y1, 512,  80,  80,  5,  3, 2, 16, 120, 4800};
    ConvHead h2 = {feat0, xth2, xtl2, wth2, wtl2, b3_2, w1_2, y2, 256,  160, 160, 10, 1, 1, 8,  320, 24000};
    conv3x3_mfma<<<720, 256, 0, stream>>>(h0, h1, h2, logits, use_xt);

    // keys + histogram from logits
    keys_kernel<<<(NBOX + 255) / 256, 256, 0, stream>>>(logits, b1_0, b1_1, b1_2, keys, hist);

    // top-256
    select_kernel<<<1, 256, 0, stream>>>(hist, meta);
    compact_kernel<<<(NBOX + 255) / 256, 256, 0, stream>>>(keys, NBOX, meta, cand, meta + 2);
    sort_select_kernel<<<1, 1024, 0, stream>>>(cand, meta, sel);

    // full 85-channel compute + decode for winners only
    final_kernel<<<256, 256, 0, stream>>>(y0, y1, y2, w1_0, w1_1, w1_2,
                                          b1_0, b1_1, b1_2, sel, (float*)d_out);
}